// Round 4
// baseline (63.633 us; speedup 1.0000x reference)
//
#include <hip/hip_runtime.h>

// Problem: out[b,h,w,i,k] = inputs[b,h,w,i] * u[i,k],
//          u[i,k] = beta[i,k]^2 / sum_k beta[i,k]^2
// Shapes: inputs (4,256,256,32) f32, beta (32,8) f32, out (...,32,8) f32.
// Memory-bound: 256 MiB write + 32 MiB read. One float4 store per
// thread-iteration (perfectly coalesced); u lives in LDS (256 floats).

#define DIMD 32
#define DIMK 8

__global__ __launch_bounds__(256) void mass_proto_kernel(
    const float* __restrict__ inputs,
    const float* __restrict__ beta,
    float* __restrict__ out,
    int n4)  // number of float4 output chunks = out_size/4
{
    __shared__ float bsq[DIMD * DIMK];
    __shared__ float u[DIMD * DIMK];

    // --- compute u (256 threads, one element each) ---
    const int t = threadIdx.x;              // 0..255
    float b = beta[t];
    bsq[t] = b * b;
    __syncthreads();
    const int row = t >> 3;                 // feature index i
    float s = 0.f;
#pragma unroll
    for (int j = 0; j < DIMK; ++j) s += bsq[row * DIMK + j];
    u[t] = bsq[t] / s;
    __syncthreads();

    const float4* __restrict__ u4 = reinterpret_cast<const float4*>(u);
    float4* __restrict__ out4 = reinterpret_cast<float4*>(out);

    // --- broadcast: each iteration emits one float4 (half a K-row) ---
    int idx = blockIdx.x * blockDim.x + threadIdx.x;
    const int stride = gridDim.x * blockDim.x;
    for (; idx < n4; idx += stride) {
        const float x = inputs[idx >> 1];   // 2 lanes share one element
        const float4 uu = u4[idx & 63];     // lane-stride-1 ds_read_b128
        float4 o;
        o.x = x * uu.x;
        o.y = x * uu.y;
        o.z = x * uu.z;
        o.w = x * uu.w;
        out4[idx] = o;                      // contiguous dwordx4 stores
    }
}

extern "C" void kernel_launch(void* const* d_in, const int* in_sizes, int n_in,
                              void* d_out, int out_size, void* d_ws, size_t ws_size,
                              hipStream_t stream) {
    const float* inputs = (const float*)d_in[0];  // (4,256,256,32)
    const float* beta   = (const float*)d_in[1];  // (32,8)
    float* out = (float*)d_out;                   // (4,256,256,32,8)

    const int n4 = out_size / 4;                  // 16,777,216 float4s
    const int threads = 256;
    const int blocks = 2048;                      // grid-stride x32, 32 waves/CU

    mass_proto_kernel<<<blocks, threads, 0, stream>>>(inputs, beta, out, n4);
}

// Round 6
// 60.776 us; speedup vs baseline: 1.0470x; 1.0470x over previous
//
#include <hip/hip_runtime.h>

// Problem: out[b,h,w,i,k] = inputs[b,h,w,i] * u[i,k],
//          u[i,k] = beta[i,k]^2 / sum_k beta[i,k]^2
// Shapes: inputs (4,256,256,32) f32, beta (32,8) f32, out (...,32,8) f32.
// Memory-bound: 256 MiB write + 32 MiB read.
//
// Round-5: fix compile error — __builtin_nontemporal_store needs a clang
// ext_vector pointer, not HIP's float4 class. Otherwise same as round 4:
//  - nontemporal stores: stream 256 MiB past L2 (stop write-allocate thrash)
//  - u4[idx&63] loop-invariant (stride % 64 == 0) -> hoisted, one LDS read
//  - x4 unroll across the grid stride for load MLP; stores stay contiguous

#define DIMD 32
#define DIMK 8

typedef float f32x4 __attribute__((ext_vector_type(4)));

__global__ __launch_bounds__(256) void mass_proto_kernel(
    const float* __restrict__ inputs,
    const float* __restrict__ beta,
    float* __restrict__ out,
    int n4)  // number of float4 output chunks = out_size/4
{
    __shared__ float bsq[DIMD * DIMK];
    __shared__ float u[DIMD * DIMK];

    // --- compute u (256 threads, one element each) ---
    const int t = threadIdx.x;              // 0..255
    float b = beta[t];
    bsq[t] = b * b;
    __syncthreads();
    const int row = t >> 3;                 // feature index i
    float s = 0.f;
#pragma unroll
    for (int j = 0; j < DIMK; ++j) s += bsq[row * DIMK + j];
    u[t] = bsq[t] / s;
    __syncthreads();

    const f32x4* __restrict__ u4 = reinterpret_cast<const f32x4*>(u);
    f32x4* __restrict__ out4 = reinterpret_cast<f32x4*>(out);

    // stride = gridDim*blockDim is a multiple of 64 -> (idx + j*stride)&63
    // is constant == tid&63. One LDS read for the whole kernel.
    const f32x4 uu = u4[t & 63];

    int idx = blockIdx.x * blockDim.x + threadIdx.x;
    const int stride = gridDim.x * blockDim.x;

    // --- main loop, x4 unrolled across the grid stride ---
    for (; idx + 3 * stride < n4; idx += 4 * stride) {
        const float x0 = inputs[(idx + 0 * stride) >> 1];
        const float x1 = inputs[(idx + 1 * stride) >> 1];
        const float x2 = inputs[(idx + 2 * stride) >> 1];
        const float x3 = inputs[(idx + 3 * stride) >> 1];

        __builtin_nontemporal_store(x0 * uu, &out4[idx + 0 * stride]);
        __builtin_nontemporal_store(x1 * uu, &out4[idx + 1 * stride]);
        __builtin_nontemporal_store(x2 * uu, &out4[idx + 2 * stride]);
        __builtin_nontemporal_store(x3 * uu, &out4[idx + 3 * stride]);
    }
    // tail (not taken for the bench shape: n4/stride == 32 exactly)
    for (; idx < n4; idx += stride) {
        __builtin_nontemporal_store(inputs[idx >> 1] * uu, &out4[idx]);
    }
}

extern "C" void kernel_launch(void* const* d_in, const int* in_sizes, int n_in,
                              void* d_out, int out_size, void* d_ws, size_t ws_size,
                              hipStream_t stream) {
    const float* inputs = (const float*)d_in[0];  // (4,256,256,32)
    const float* beta   = (const float*)d_in[1];  // (32,8)
    float* out = (float*)d_out;                   // (4,256,256,32,8)

    const int n4 = out_size / 4;                  // 16,777,216 float4s
    const int threads = 256;
    const int blocks = 2048;                      // 8 blocks/CU, 32 waves/CU

    mass_proto_kernel<<<blocks, threads, 0, stream>>>(inputs, beta, out, n4);
}